// Round 13
// baseline (3443.731 us; speedup 1.0000x reference)
//
#include <hip/hip_runtime.h>

typedef __attribute__((ext_vector_type(4))) float f32x4;
typedef __attribute__((ext_vector_type(8))) short s16x8;

#define LOG2E 1.4426950408889634f
#define K2L   2.8853900817779268f  /* 2*log2(e) */

__device__ __forceinline__ unsigned short f2bf(float f) {
  union { float f; unsigned int i; } v; v.f = f;
  unsigned int u = v.i;
  u = (u + 0x7FFFu + ((u >> 16) & 1u)) >> 16;
  return (unsigned short)u;
}
__device__ __forceinline__ float bf2f(unsigned short s) {
  union { unsigned int i; float f; } v; v.i = ((unsigned int)s) << 16;
  return v.f;
}
__device__ __forceinline__ float rcp_(float x) { return __builtin_amdgcn_rcpf(x); }
__device__ __forceinline__ float ex2(float x) { return __builtin_amdgcn_exp2f(x); }
__device__ __forceinline__ f32x4 mfma16(s16x8 a, s16x8 b, f32x4 c) {
  return __builtin_amdgcn_mfma_f32_16x16x32_bf16(a, b, c, 0, 0, 0);
}
__device__ __forceinline__ s16x8 pack8s(const float* s, float sc) {
  s16x8 v;
#pragma unroll
  for (int j = 0; j < 8; ++j) v[j] = (short)f2bf(s[j] * sc);
  return v;
}

// ws offsets (bytes)
#define OFF_H0   0            /* 134217728: h0 bf16 [8e][1024t][32b][256] */
#define OFF_XW   134217728    /* 67108864: 2 x 32MB xw ring */
#define OFF_XT   201326592    /* 8388608: xt bf16 [1024t][32b][128] */
#define OFF_WHH  209715200    /* 4194304: whhb bf16 (pre-scaled) */
#define OFF_H1C  213909504    /* 16777216: 2 x 8MB h1 chunk [8e][64ss][32b][256] */
#define OFF_HST  230686720    /* 131072 */
#define OFF_CST  230817792    /* 262144 */
#define OFF_M    231079936    /* 49152: M f32 [2][48][128] */
#define OFF_CV   231129088    /* 256 */
#define OFF_G    231129344    /* 1024 */
#define OFF_WIH0 231130368    /* 2097152: wihb0 bf16 [16ed][512n][128k] pre-scaled */
#define OFF_WIH1 233227520    /* 4194304: wihb1 bf16 [16ed][512n][256k] pre-scaled */
#define OFF_BIA  237421824    /* 131072: biasb f32 [2L][16ed][512] pre-scaled */
#define WS_NEED  237552896

// ---------------------------------------------------------------- ws diag
__global__ void wsdbg_kernel(float* __restrict__ out, float v) { out[0] = v; }

// ---------------------------------------------------------------- prep: pre-scaled bf16 weights + biases
__global__ void prep_kernel(const float* __restrict__ Whh0, const float* __restrict__ Whh1,
                            const float* __restrict__ Wih0, const float* __restrict__ Wih1,
                            const float* __restrict__ bih0, const float* __restrict__ bhh0,
                            const float* __restrict__ bih1, const float* __restrict__ bhh1,
                            unsigned short* __restrict__ whhb,
                            unsigned short* __restrict__ wihb0,
                            unsigned short* __restrict__ wihb1,
                            float* __restrict__ biasb) {
  const int tid = blockIdx.x * 512 + threadIdx.x;  // 2,097,152 threads
  for (int i = tid; i < 5242880; i += 2097152) {
    if (i < 2097152) {
      const int gate = (i >> 14) & 3;
      const float sc = (gate == 2) ? K2L : -LOG2E;
      whhb[i] = f2bf((i < 1048576 ? Whh0[i] : Whh1[i - 1048576]) * sc);
    } else if (i < 3145728) {
      const int j = i - 2097152;
      const int gate = (j >> 14) & 3;  // k=128
      const float sc = (gate == 2) ? K2L : -LOG2E;
      wihb0[j] = f2bf(Wih0[j] * sc);
    } else {
      const int j = i - 3145728;
      const int gate = (j >> 15) & 3;  // k=256
      const float sc = (gate == 2) ? K2L : -LOG2E;
      wihb1[j] = f2bf(Wih1[j] * sc);
    }
  }
  if (tid < 16384) {
    const int L = tid >> 13, rem = tid & 8191;
    const int gate = (rem >> 7) & 3;
    const float sc = (gate == 2) ? K2L : -LOG2E;
    const float b = L ? (bih1[rem] + bhh1[rem]) : (bih0[rem] + bhh0[rem]);
    biasb[tid] = b * sc;
  }
}

// ---------------------------------------------------------------- prep: x -> xt bf16 [t][b][128]
__global__ void prepx_kernel(const float* __restrict__ x, unsigned short* __restrict__ xt) {
  const int i = blockIdx.x * 512 + threadIdx.x;
  for (int j = i; j < 4194304; j += 2097152) {
    const int b = j >> 17, rem = j & 131071, t = rem >> 7, f = rem & 127;
    xt[((size_t)t * 32 + b) * 128 + f] = f2bf(x[j]);
  }
}

// ---------------------------------------------------------------- prep: M = fc_w @ fc1_w halves; Cv = fc_w@fc1_b + fc_b
__global__ void mprep_kernel(const float* __restrict__ fc1w, const float* __restrict__ fc1b,
                             const float* __restrict__ fcw, const float* __restrict__ fcb,
                             float* __restrict__ M, float* __restrict__ Cv) {
  const int mi = blockIdx.x * 256 + threadIdx.x;  // grid 48
  if (mi < 12288) {  // [2][48][128]
    const int dd = mi / 6144, rem = mi % 6144, o = rem >> 7, hc = rem & 127;
    float s = 0.f;
    if (o < 44)
      for (int h = 0; h < 128; ++h) s += fcw[o * 128 + h] * fc1w[h * 256 + dd * 128 + hc];
    M[mi] = s;
  }
  if (blockIdx.x == 0 && threadIdx.x < 44) {
    const int o = threadIdx.x;
    float s = fcb[o];
    for (int h = 0; h < 128; ++h) s += fcw[o * 128 + h] * fc1b[h];
    Cv[o] = s;
  }
}

// ---------------------------------------------------------------- out init: out[t,b,o] = Cv[o]
__global__ void initout_kernel(const float* __restrict__ Cv, float* __restrict__ out) {
  const int i = blockIdx.x * 512 + threadIdx.x;
  if (i < 1441792) out[i] = Cv[i % 44];
}

// ---------------------------------------------------------------- gating: gates + loss
__global__ void gating_kernel(const float* __restrict__ spk,
                              const float* __restrict__ wgw,
                              const float* __restrict__ wgb,
                              float* __restrict__ gates_out,
                              float* __restrict__ loss_out) {
  __shared__ __align__(16) float logits[32][8];
  __shared__ __align__(16) float gmat[32][8];
  const int tid = threadIdx.x;
  {
    const int b = tid >> 3, e = tid & 7;
    float s = wgb[e];
    for (int k = 0; k < 256; ++k) s += spk[b * 256 + k] * wgw[e * 256 + k];
    logits[b][e] = s;
  }
  __syncthreads();
  if (tid < 32) {
    const int b = tid;
    float v[8];
    for (int e = 0; e < 8; ++e) v[e] = logits[b][e];
    int idx[4]; float val[4];
    unsigned used = 0;
    for (int k = 0; k < 4; ++k) {
      float best = -1e30f; int bi = 0;
      for (int e = 0; e < 8; ++e)
        if (!((used >> e) & 1) && v[e] > best) { best = v[e]; bi = e; }
      used |= (1u << bi); idx[k] = bi; val[k] = best;
    }
    const float m = val[0];
    float ex[4], ssum = 0.f;
    for (int k = 0; k < 4; ++k) { ex[k] = ex2(LOG2E * (val[k] - m)); ssum += ex[k]; }
    for (int e = 0; e < 8; ++e) gmat[b][e] = 0.f;
    for (int k = 0; k < 4; ++k) gmat[b][idx[k]] = ex[k] / ssum;
    for (int e = 0; e < 8; ++e) gates_out[b * 8 + e] = gmat[b][e];
  }
  __syncthreads();
  if (tid == 0) {
    float imp[8], ld[8];
    for (int e = 0; e < 8; ++e) {
      float si = 0.f, sl = 0.f;
      for (int b = 0; b < 32; ++b) { si += gmat[b][e]; sl += (gmat[b][e] > 0.f) ? 1.f : 0.f; }
      imp[e] = si; ld[e] = sl;
    }
    float mi = 0.f, ml = 0.f;
    for (int e = 0; e < 8; ++e) { mi += imp[e]; ml += ld[e]; }
    mi *= 0.125f; ml *= 0.125f;
    float vi = 0.f, vl = 0.f;
    for (int e = 0; e < 8; ++e) {
      vi += (imp[e] - mi) * (imp[e] - mi);
      vl += (ld[e] - ml) * (ld[e] - ml);
    }
    vi /= 7.f; vl /= 7.f;
    loss_out[0] = 0.01f * (vi / (mi * mi + 1e-10f) + vl / (ml * ml + 1e-10f));
  }
}

// ---------------------------------------------------------------- fused: rec (blk<16, 2 chains) | gemm (16..127) | fold (>=128, L1)
// 1024 threads, __launch_bounds__(1024,1): VGPR cap 128 (16 waves must fit a CU),
// weights stay register-resident. Rec block = one (e,d), BOTH bh chains
// (16 waves = 4/SIMD): independent chains issue while the other stalls.
// xw: ushort [ed2*2+bh][64 ss][512 n][16 b]; n = gate*128 + cell (pre-scaled).
// LDS h slot per chain: (cell,b) at byte (cell>>5)<<10 | ((cell>>3)&3)<<8 | b<<4 | (cell&7)<<1.
template <int L>
__global__ __launch_bounds__(1024, 1) void fused(
    int k,
    const unsigned short* __restrict__ Asrc,
    const unsigned short* __restrict__ wihb,
    const float* __restrict__ biasb,
    const unsigned short* __restrict__ whhb,
    unsigned short* __restrict__ xwbufs,
    unsigned short* __restrict__ hstate, float* __restrict__ cstate,
    unsigned short* __restrict__ hout,
    const float* __restrict__ Mmat, const float* __restrict__ gatesp,
    float* __restrict__ outp) {
  constexpr int KC = L ? 8 : 4;
  constexpr int KS = KC * 32;
  __shared__ __align__(16) char hbf[2][2][4096];
  const int tid = threadIdx.x, w = tid >> 6, l = tid & 63;
  const int l15 = l & 15, lq = l >> 4;

  if (L && blockIdx.x >= 128) {
    // ================= FOLD role: chunk c2 = k-2; 2 ss per block =================
    const int c2 = k - 2;
    if (c2 < 0 || c2 > 15) return;
    const int w8 = w & 7;
    if (w8 >= 6) return;
    const int fb = blockIdx.x - 128;           // 0..31
    const int ss = fb * 2 + (w >> 3);
    const int mt = (w8 >= 3) ? 1 : 0, ot = w8 - mt * 3;
    const int o = ot * 16 + l15;
    const bool ov = o < 44;
    s16x8 bfm[2][4];
#pragma unroll
    for (int dd = 0; dd < 2; ++dd)
#pragma unroll
      for (int kc = 0; kc < 4; ++kc) {
        if (ov) bfm[dd][kc] = pack8s(Mmat + ((size_t)dd * 48 + o) * 128 + kc * 32 + lq * 8, 1.f);
        else { s16x8 z = {0,0,0,0,0,0,0,0}; bfm[dd][kc] = z; }
      }
    const unsigned short* hb = hout + (size_t)(c2 & 1) * 4194304;
    f32x4 acc0 = {0.f,0.f,0.f,0.f}, acc1 = {0.f,0.f,0.f,0.f};
    for (int e = 0; e < 8; ++e) {
      const unsigned short* ap = hb + ((((size_t)e * 64 + ss) * 32) + mt * 16 + l15) * 256 + lq * 8;
      f32x4 p0 = {0.f,0.f,0.f,0.f}, p1 = {0.f,0.f,0.f,0.f};
#pragma unroll
      for (int kc = 0; kc < 4; ++kc) {
        s16x8 a0 = *(const s16x8*)(ap + kc * 32);
        s16x8 a1 = *(const s16x8*)(ap + 128 + kc * 32);
        p0 = mfma16(a0, bfm[0][kc], p0);
        p1 = mfma16(a1, bfm[1][kc], p1);
      }
#pragma unroll
      for (int r = 0; r < 4; ++r) {
        const float g = gatesp[(mt * 16 + lq * 4 + r) * 8 + e];
        acc0[r] += g * p0[r];
        acc1[r] += g * p1[r];
      }
    }
    if (ov) {
      const int s2 = c2 * 64 + ss, t1 = 1023 - s2;
#pragma unroll
      for (int r = 0; r < 4; ++r) {
        const int b = mt * 16 + lq * 4 + r;
        outp[((size_t)s2 * 32 + b) * 44 + o] += acc0[r];
        outp[((size_t)t1 * 32 + b) * 44 + o] += acc1[r];
      }
    }
    return;
  }

  if (blockIdx.x >= 16) {
    // ================= GEMM role: xw chunk k; 16 waves x 2 N-tiles =================
    if (k >= 16) return;
    const int gb = blockIdx.x - 16;            // 0..111
    const int ed = gb & 15, e = ed >> 1, d = ed & 1;
    const int slice = gb >> 4;                 // 0..6
    unsigned short* xw = xwbufs + (size_t)(k & 1) * 16777216;

    s16x8 bf[2][KC];
    float bias[2];
#pragma unroll
    for (int j = 0; j < 2; ++j) {
      const int n = w * 32 + j * 16 + l15;
      bias[j] = biasb[ed * 512 + n];
      const unsigned short* wp = wihb + ((size_t)ed * 512 + n) * KS + lq * 8;
#pragma unroll
      for (int kc = 0; kc < KC; ++kc) bf[j][kc] = *(const s16x8*)(wp + kc * 32);
    }
    for (int ss = slice; ss < 64; ss += 7) {
      const int s = k * 64 + ss;
      const int t = d ? 1023 - s : s;
#pragma unroll
      for (int mt = 0; mt < 2; ++mt) {
        const size_t arow = (size_t)(L ? (e * 1024 + t) : t) * 32 + mt * 16 + l15;
        const unsigned short* ap = Asrc + arow * KS + lq * 8;
        s16x8 af[KC];
#pragma unroll
        for (int kc = 0; kc < KC; ++kc) af[kc] = *(const s16x8*)(ap + kc * 32);
        f32x4 acc[2];
#pragma unroll
        for (int j = 0; j < 2; ++j) acc[j] = f32x4{bias[j], bias[j], bias[j], bias[j]};
#pragma unroll
        for (int kc = 0; kc < KC; ++kc) {
#pragma unroll
          for (int j = 0; j < 2; ++j) acc[j] = mfma16(af[kc], bf[j][kc], acc[j]);
        }
        unsigned short* op = xw + (((size_t)(ed * 2 + mt) * 64 + ss) * 512) * 16 + lq * 4;
#pragma unroll
        for (int j = 0; j < 2; ++j) {
          const int n = w * 32 + j * 16 + l15;
          ushort4 o4;
          o4.x = f2bf(acc[j][0]); o4.y = f2bf(acc[j][1]);
          o4.z = f2bf(acc[j][2]); o4.w = f2bf(acc[j][3]);
          *(ushort4*)(op + (size_t)n * 16) = o4;
        }
      }
    }
    return;
  }

  // ================= REC role: chunk c = k-1; 2 chains (bh) per block ============
  const int c = k - 1;
  if (c < 0 || c > 15) return;
  __builtin_amdgcn_s_setprio(2);
  const int ed2 = blockIdx.x;                  // 0..15
  const int ch = tid >> 9;                     // bh chain
  const int t5 = tid & 511;
  const int w5 = t5 >> 6, l5 = t5 & 63;
  const int l15r = l5 & 15, lqr = l5 >> 4;
  const int e = ed2 >> 1, d = ed2 & 1;
  const int cell = w5 * 16 + l15r;
  const int sidx = ed2 * 2 + ch;               // legacy state index

  s16x8 bfh[4][4];  // pre-scaled Whh (same for both chains -> L1-cached)
#pragma unroll
  for (int g = 0; g < 4; ++g) {
    const unsigned short* wp = whhb + ((size_t)ed2 * 512 + g * 128 + cell) * 128 + lqr * 8;
#pragma unroll
    for (int kc = 0; kc < 4; ++kc) bfh[g][kc] = *(const s16x8*)(wp + kc * 32);
  }
  const int wb0 = ((cell >> 5) << 10) | (((cell >> 3) & 3) << 8) | ((cell & 7) << 1);
  float cst[4];
  unsigned short hb4[4];
  if (c == 0) {
#pragma unroll
    for (int r = 0; r < 4; ++r) { cst[r] = 0.f; hb4[r] = 0; }
    if (t5 < 256) {
      s16x8 z = {0,0,0,0,0,0,0,0};
      *(s16x8*)(&hbf[ch][0][t5 * 16]) = z;
    }
  } else {
    const float* cp = cstate + ((size_t)sidx * 512 + t5) * 4;
    const unsigned short* hp = hstate + ((size_t)sidx * 512 + t5) * 4;
#pragma unroll
    for (int r = 0; r < 4; ++r) {
      cst[r] = cp[r];
      hb4[r] = hp[r];
      *(unsigned short*)(&hbf[ch][0][wb0 | ((lqr * 4 + r) << 4)]) = hp[r];
    }
  }
  __syncthreads();

  const unsigned short* xwb =
      xwbufs + (size_t)(c & 1) * 16777216 + ((size_t)(ed2 * 2 + ch) * 64) * 8192 + cell * 16 + lqr * 4;
  const int brow = ch * 16 + lqr * 4;

  ushort4 xq[4];
#pragma unroll
  for (int g = 0; g < 4; ++g) xq[g] = *(const ushort4*)(xwb + g * 2048);

  for (int tt = 0; tt < 64; ++tt) {
    const int p = tt & 1;
    // early: prefetch next xw
    ushort4 nxq[4];
    {
      const int tn = tt < 63 ? tt + 1 : 63;
#pragma unroll
      for (int g = 0; g < 4; ++g) nxq[g] = *(const ushort4*)(xwb + (size_t)tn * 8192 + g * 2048);
    }
    // early: store previous step's h from register carry
    if (tt > 0) {
      const int ptt = tt - 1;
      size_t ob;
      if (L) {
        ob = (size_t)(c & 1) * 4194304 + (((size_t)e * 64 + ptt) * 32 + brow) * 256 + d * 128 + cell;
      } else {
        const int s = c * 64 + ptt;
        const int tg = d ? 1023 - s : s;
        ob = (((size_t)e * 1024 + tg) * 32 + brow) * 256 + d * 128 + cell;
      }
#pragma unroll
      for (int r = 0; r < 4; ++r) hout[ob + (size_t)r * 256] = hb4[r];
    }

    s16x8 hf[4];
#pragma unroll
    for (int kc = 0; kc < 4; ++kc) hf[kc] = *(const s16x8*)(&hbf[ch][p][kc * 1024 + l5 * 16]);
    f32x4 a[4];
#pragma unroll
    for (int g = 0; g < 4; ++g) {
      a[g][0] = bf2f(xq[g].x); a[g][1] = bf2f(xq[g].y);
      a[g][2] = bf2f(xq[g].z); a[g][3] = bf2f(xq[g].w);
    }
#pragma unroll
    for (int kc = 0; kc < 4; ++kc) {
#pragma unroll
      for (int g = 0; g < 4; ++g) a[g] = mfma16(hf[kc], bfh[g][kc], a[g]);
    }

    // gates (pre-scaled inputs; overflow-safe clamps)
#pragma unroll
    for (int r = 0; r < 4; ++r) {
      const float ai = ex2(a[0][r]);
      const float af = ex2(a[1][r]);
      const float bg = ex2(fminf(a[2][r], 80.f));
      const float ao = ex2(a[3][r]);
      const float sf = rcp_(1.f + af);
      const float r1 = rcp_((1.f + ai) * (1.f + bg));
      const float bgm = __builtin_fmaf(bg, K2L, -K2L);
      const float cc = __builtin_fmaf(sf, cst[r], bgm * r1);
      cst[r] = cc;
      const float qc = ex2(fminf(cc, 80.f));
      const float r2 = rcp_((1.f + ao) * (1.f + qc));
      hb4[r] = f2bf((qc - 1.f) * r2);
    }
    char* hw = &hbf[ch][1 - p][0];
#pragma unroll
    for (int r = 0; r < 4; ++r)
      *(unsigned short*)(hw + (wb0 | ((lqr * 4 + r) << 4))) = hb4[r];
    __syncthreads();
#pragma unroll
    for (int g = 0; g < 4; ++g) xq[g] = nxq[g];
  }

  // epilogue: store h(63) + carry state
  {
    size_t ob;
    if (L) {
      ob = (size_t)(c & 1) * 4194304 + (((size_t)e * 64 + 63) * 32 + brow) * 256 + d * 128 + cell;
    } else {
      const int s = c * 64 + 63;
      const int tg = d ? 1023 - s : s;
      ob = (((size_t)e * 1024 + tg) * 32 + brow) * 256 + d * 128 + cell;
    }
#pragma unroll
    for (int r = 0; r < 4; ++r) hout[ob + (size_t)r * 256] = hb4[r];
    unsigned short* hsp = hstate + ((size_t)sidx * 512 + t5) * 4;
    float* csp = cstate + ((size_t)sidx * 512 + t5) * 4;
#pragma unroll
    for (int r = 0; r < 4; ++r) { hsp[r] = hb4[r]; csp[r] = cst[r]; }
  }
  __builtin_amdgcn_s_setprio(0);
}

// ---------------------------------------------------------------- launch
extern "C" void kernel_launch(void* const* d_in, const int* in_sizes, int n_in,
                              void* d_out, int out_size, void* d_ws, size_t ws_size,
                              hipStream_t stream) {
  const float* x    = (const float*)d_in[0];
  const float* spk  = (const float*)d_in[1];
  const float* wgw  = (const float*)d_in[2];
  const float* wgb  = (const float*)d_in[3];
  const float* Wih0 = (const float*)d_in[4];
  const float* Whh0 = (const float*)d_in[5];
  const float* bih0 = (const float*)d_in[6];
  const float* bhh0 = (const float*)d_in[7];
  const float* Wih1 = (const float*)d_in[8];
  const float* Whh1 = (const float*)d_in[9];
  const float* bih1 = (const float*)d_in[10];
  const float* bhh1 = (const float*)d_in[11];
  const float* fc1w = (const float*)d_in[12];
  const float* fc1b = (const float*)d_in[13];
  const float* fcw  = (const float*)d_in[14];
  const float* fcb  = (const float*)d_in[15];
  float* out = (float*)d_out;

  if (ws_size < (size_t)WS_NEED) {
    wsdbg_kernel<<<1, 1, 0, stream>>>(out, (float)(ws_size >> 20));
    return;
  }
  char* ws = (char*)d_ws;
  unsigned short* h0     = (unsigned short*)(ws + OFF_H0);
  unsigned short* xwbufs = (unsigned short*)(ws + OFF_XW);
  unsigned short* xt     = (unsigned short*)(ws + OFF_XT);
  unsigned short* whhb   = (unsigned short*)(ws + OFF_WHH);
  unsigned short* h1c    = (unsigned short*)(ws + OFF_H1C);
  unsigned short* hstate = (unsigned short*)(ws + OFF_HST);
  float*          cstate = (float*)(ws + OFF_CST);
  float*          Mmat   = (float*)(ws + OFF_M);
  float*          Cv     = (float*)(ws + OFF_CV);
  float*          gatesw = (float*)(ws + OFF_G);
  unsigned short* wihb0  = (unsigned short*)(ws + OFF_WIH0);
  unsigned short* wihb1  = (unsigned short*)(ws + OFF_WIH1);
  float*          biasb  = (float*)(ws + OFF_BIA);

  prep_kernel<<<4096, 512, 0, stream>>>(Whh0, Whh1, Wih0, Wih1, bih0, bhh0, bih1, bhh1,
                                        whhb, wihb0, wihb1, biasb);
  prepx_kernel<<<4096, 512, 0, stream>>>(x, xt);
  mprep_kernel<<<48, 256, 0, stream>>>(fc1w, fc1b, fcw, fcb, Mmat, Cv);
  initout_kernel<<<2816, 512, 0, stream>>>(Cv, out);
  gating_kernel<<<1, 256, 0, stream>>>(spk, wgw, wgb, gatesw, out + 1441792);

  for (int k = 0; k <= 16; ++k)
    fused<0><<<128, 1024, 0, stream>>>(k, xt, wihb0, biasb, whhb, xwbufs,
                                       hstate, cstate, h0, nullptr, nullptr, out);
  for (int k = 0; k <= 17; ++k)
    fused<1><<<160, 1024, 0, stream>>>(k, h0, wihb1, biasb + 8192, whhb + 1048576, xwbufs,
                                       hstate, cstate, h1c, Mmat, gatesw, out);
}

// Round 14
// 2245.526 us; speedup vs baseline: 1.5336x; 1.5336x over previous
//
#include <hip/hip_runtime.h>

typedef __attribute__((ext_vector_type(4))) float f32x4;
typedef __attribute__((ext_vector_type(8))) short s16x8;

#define LOG2E 1.4426950408889634f
#define K2L   2.8853900817779268f  /* 2*log2(e) */

__device__ __forceinline__ unsigned short f2bf(float f) {
  union { float f; unsigned int i; } v; v.f = f;
  unsigned int u = v.i;
  u = (u + 0x7FFFu + ((u >> 16) & 1u)) >> 16;
  return (unsigned short)u;
}
__device__ __forceinline__ float bf2f(unsigned short s) {
  union { unsigned int i; float f; } v; v.i = ((unsigned int)s) << 16;
  return v.f;
}
__device__ __forceinline__ float rcp_(float x) { return __builtin_amdgcn_rcpf(x); }
__device__ __forceinline__ float ex2(float x) { return __builtin_amdgcn_exp2f(x); }
__device__ __forceinline__ f32x4 mfma16(s16x8 a, s16x8 b, f32x4 c) {
  return __builtin_amdgcn_mfma_f32_16x16x32_bf16(a, b, c, 0, 0, 0);
}
__device__ __forceinline__ s16x8 pack8s(const float* s, float sc) {
  s16x8 v;
#pragma unroll
  for (int j = 0; j < 8; ++j) v[j] = (short)f2bf(s[j] * sc);
  return v;
}

// ws offsets (bytes)
#define OFF_H0   0            /* 134217728: h0 bf16 [8e][1024t][32b][256] */
#define OFF_XW   134217728    /* 67108864: 2 x 32MB xw ring, [ed2*2+mt][64ss][16b][512n] */
#define OFF_XT   201326592    /* 8388608: xt bf16 [1024t][32b][128] */
#define OFF_WHH  209715200    /* 4194304: whhb bf16 (pre-scaled) */
#define OFF_H1C  213909504    /* 16777216: 2 x 8MB h1 chunk [8e][64ss][32b][256] */
#define OFF_HST  230686720    /* 131072 */
#define OFF_CST  230817792    /* 262144 */
#define OFF_M    231079936    /* 49152: M f32 [2][48][128] */
#define OFF_CV   231129088    /* 256 */
#define OFF_G    231129344    /* 1024 */
#define OFF_WIH0 231130368    /* 2097152: wihb0 bf16 [16ed][512n][128k] pre-scaled */
#define OFF_WIH1 233227520    /* 4194304: wihb1 bf16 [16ed][512n][256k] pre-scaled */
#define OFF_BIA  237421824    /* 131072: biasb f32 [2L][16ed][512] pre-scaled */
#define WS_NEED  237552896

// ---------------------------------------------------------------- ws diag
__global__ void wsdbg_kernel(float* __restrict__ out, float v) { out[0] = v; }

// ---------------------------------------------------------------- prep: pre-scaled bf16 weights + biases
__global__ void prep_kernel(const float* __restrict__ Whh0, const float* __restrict__ Whh1,
                            const float* __restrict__ Wih0, const float* __restrict__ Wih1,
                            const float* __restrict__ bih0, const float* __restrict__ bhh0,
                            const float* __restrict__ bih1, const float* __restrict__ bhh1,
                            unsigned short* __restrict__ whhb,
                            unsigned short* __restrict__ wihb0,
                            unsigned short* __restrict__ wihb1,
                            float* __restrict__ biasb) {
  const int tid = blockIdx.x * 512 + threadIdx.x;  // 2,097,152 threads
  for (int i = tid; i < 5242880; i += 2097152) {
    if (i < 2097152) {
      const int gate = (i >> 14) & 3;
      const float sc = (gate == 2) ? K2L : -LOG2E;
      whhb[i] = f2bf((i < 1048576 ? Whh0[i] : Whh1[i - 1048576]) * sc);
    } else if (i < 3145728) {
      const int j = i - 2097152;
      const int gate = (j >> 14) & 3;  // k=128
      const float sc = (gate == 2) ? K2L : -LOG2E;
      wihb0[j] = f2bf(Wih0[j] * sc);
    } else {
      const int j = i - 3145728;
      const int gate = (j >> 15) & 3;  // k=256
      const float sc = (gate == 2) ? K2L : -LOG2E;
      wihb1[j] = f2bf(Wih1[j] * sc);
    }
  }
  if (tid < 16384) {
    const int L = tid >> 13, rem = tid & 8191;
    const int gate = (rem >> 7) & 3;
    const float sc = (gate == 2) ? K2L : -LOG2E;
    const float b = L ? (bih1[rem] + bhh1[rem]) : (bih0[rem] + bhh0[rem]);
    biasb[tid] = b * sc;
  }
}

// ---------------------------------------------------------------- prep: x -> xt bf16 [t][b][128]
__global__ void prepx_kernel(const float* __restrict__ x, unsigned short* __restrict__ xt) {
  const int i = blockIdx.x * 512 + threadIdx.x;
  for (int j = i; j < 4194304; j += 2097152) {
    const int b = j >> 17, rem = j & 131071, t = rem >> 7, f = rem & 127;
    xt[((size_t)t * 32 + b) * 128 + f] = f2bf(x[j]);
  }
}

// ---------------------------------------------------------------- prep: M = fc_w @ fc1_w halves; Cv = fc_w@fc1_b + fc_b
__global__ void mprep_kernel(const float* __restrict__ fc1w, const float* __restrict__ fc1b,
                             const float* __restrict__ fcw, const float* __restrict__ fcb,
                             float* __restrict__ M, float* __restrict__ Cv) {
  const int mi = blockIdx.x * 256 + threadIdx.x;  // grid 48
  if (mi < 12288) {  // [2][48][128]
    const int dd = mi / 6144, rem = mi % 6144, o = rem >> 7, hc = rem & 127;
    float s = 0.f;
    if (o < 44)
      for (int h = 0; h < 128; ++h) s += fcw[o * 128 + h] * fc1w[h * 256 + dd * 128 + hc];
    M[mi] = s;
  }
  if (blockIdx.x == 0 && threadIdx.x < 44) {
    const int o = threadIdx.x;
    float s = fcb[o];
    for (int h = 0; h < 128; ++h) s += fcw[o * 128 + h] * fc1b[h];
    Cv[o] = s;
  }
}

// ---------------------------------------------------------------- out init: out[t,b,o] = Cv[o]
__global__ void initout_kernel(const float* __restrict__ Cv, float* __restrict__ out) {
  const int i = blockIdx.x * 512 + threadIdx.x;
  if (i < 1441792) out[i] = Cv[i % 44];
}

// ---------------------------------------------------------------- gating: gates + loss
__global__ void gating_kernel(const float* __restrict__ spk,
                              const float* __restrict__ wgw,
                              const float* __restrict__ wgb,
                              float* __restrict__ gates_out,
                              float* __restrict__ loss_out) {
  __shared__ __align__(16) float logits[32][8];
  __shared__ __align__(16) float gmat[32][8];
  const int tid = threadIdx.x;
  {
    const int b = tid >> 3, e = tid & 7;
    float s = wgb[e];
    for (int k = 0; k < 256; ++k) s += spk[b * 256 + k] * wgw[e * 256 + k];
    logits[b][e] = s;
  }
  __syncthreads();
  if (tid < 32) {
    const int b = tid;
    float v[8];
    for (int e = 0; e < 8; ++e) v[e] = logits[b][e];
    int idx[4]; float val[4];
    unsigned used = 0;
    for (int k = 0; k < 4; ++k) {
      float best = -1e30f; int bi = 0;
      for (int e = 0; e < 8; ++e)
        if (!((used >> e) & 1) && v[e] > best) { best = v[e]; bi = e; }
      used |= (1u << bi); idx[k] = bi; val[k] = best;
    }
    const float m = val[0];
    float ex[4], ssum = 0.f;
    for (int k = 0; k < 4; ++k) { ex[k] = ex2(LOG2E * (val[k] - m)); ssum += ex[k]; }
    for (int e = 0; e < 8; ++e) gmat[b][e] = 0.f;
    for (int k = 0; k < 4; ++k) gmat[b][idx[k]] = ex[k] / ssum;
    for (int e = 0; e < 8; ++e) gates_out[b * 8 + e] = gmat[b][e];
  }
  __syncthreads();
  if (tid == 0) {
    float imp[8], ld[8];
    for (int e = 0; e < 8; ++e) {
      float si = 0.f, sl = 0.f;
      for (int b = 0; b < 32; ++b) { si += gmat[b][e]; sl += (gmat[b][e] > 0.f) ? 1.f : 0.f; }
      imp[e] = si; ld[e] = sl;
    }
    float mi = 0.f, ml = 0.f;
    for (int e = 0; e < 8; ++e) { mi += imp[e]; ml += ld[e]; }
    mi *= 0.125f; ml *= 0.125f;
    float vi = 0.f, vl = 0.f;
    for (int e = 0; e < 8; ++e) {
      vi += (imp[e] - mi) * (imp[e] - mi);
      vl += (ld[e] - ml) * (ld[e] - ml);
    }
    vi /= 7.f; vl /= 7.f;
    loss_out[0] = 0.01f * (vi / (mi * mi + 1e-10f) + vl / (ml * ml + 1e-10f));
  }
}

// ---------------------------------------------------------------- fused: gemm (chunk k) | rec (k-1) | fold (k-2, L1)
// TRANSPOSED scheme: rec/gemm MFMAs computed as D' = W·h (operand swap; same
// fragments, transposed D). Each rec thread owns (row=l&15, cells w*16+lq*4..+3):
// -> h LDS write = 1x b64; global h-store = 1x ushort4; reads b128 XOR-swizzled.
// xw layout: [ed2*2+mt][64 ss][16 row][512 n] (n = gate*128 + cell).
// h0 / h1c global layouts unchanged.
template <int L>
__global__ __launch_bounds__(512, 1) void fused(
    int k,
    const unsigned short* __restrict__ Asrc,
    const unsigned short* __restrict__ wihb,
    const float* __restrict__ biasb,
    const unsigned short* __restrict__ whhb,
    unsigned short* __restrict__ xwbufs,
    unsigned short* __restrict__ hstate, float* __restrict__ cstate,
    unsigned short* __restrict__ hout,
    const float* __restrict__ Mmat, const float* __restrict__ gatesp,
    float* __restrict__ outp) {
  constexpr int KC = L ? 8 : 4;
  constexpr int KS = KC * 32;
  const int tid = threadIdx.x, w = tid >> 6, l = tid & 63;
  const int l15 = l & 15, lq = l >> 4;

  if (L && blockIdx.x >= 192) {
    // ================= FOLD role: chunk c2 = k-2 (unchanged) =================
    const int c2 = k - 2;
    if (c2 < 0 || c2 > 15) return;
    if (w >= 6) return;
    const int ss = blockIdx.x - 192;
    const int mt = (w >= 3) ? 1 : 0, ot = w - mt * 3;
    const int o = ot * 16 + l15;
    const bool ov = o < 44;
    s16x8 bfm[2][4];
#pragma unroll
    for (int dd = 0; dd < 2; ++dd)
#pragma unroll
      for (int kc = 0; kc < 4; ++kc) {
        if (ov) bfm[dd][kc] = pack8s(Mmat + ((size_t)dd * 48 + o) * 128 + kc * 32 + lq * 8, 1.f);
        else { s16x8 z = {0,0,0,0,0,0,0,0}; bfm[dd][kc] = z; }
      }
    const unsigned short* hb = hout + (size_t)(c2 & 1) * 4194304;
    f32x4 acc0 = {0.f,0.f,0.f,0.f}, acc1 = {0.f,0.f,0.f,0.f};
    for (int e = 0; e < 8; ++e) {
      const unsigned short* ap = hb + ((((size_t)e * 64 + ss) * 32) + mt * 16 + l15) * 256 + lq * 8;
      f32x4 p0 = {0.f,0.f,0.f,0.f}, p1 = {0.f,0.f,0.f,0.f};
#pragma unroll
      for (int kc = 0; kc < 4; ++kc) {
        s16x8 a0 = *(const s16x8*)(ap + kc * 32);
        s16x8 a1 = *(const s16x8*)(ap + 128 + kc * 32);
        p0 = mfma16(a0, bfm[0][kc], p0);
        p1 = mfma16(a1, bfm[1][kc], p1);
      }
#pragma unroll
      for (int r = 0; r < 4; ++r) {
        const float g = gatesp[(mt * 16 + lq * 4 + r) * 8 + e];
        acc0[r] += g * p0[r];
        acc1[r] += g * p1[r];
      }
    }
    if (ov) {
      const int s2 = c2 * 64 + ss, t1 = 1023 - s2;
#pragma unroll
      for (int r = 0; r < 4; ++r) {
        const int b = mt * 16 + lq * 4 + r;
        outp[((size_t)s2 * 32 + b) * 44 + o] += acc0[r];
        outp[((size_t)t1 * 32 + b) * 44 + o] += acc1[r];
      }
    }
    return;
  }

  if (blockIdx.x >= 32) {
    // ================= GEMM role: xw chunk k (swapped operands) =================
    if (k >= 16) return;
    const int gb = blockIdx.x - 32;
    const int ed = gb & 15, e = ed >> 1, d = ed & 1;
    const int slice = gb >> 4;
    const int nsl = L ? 10 : 14;
    unsigned short* xw = xwbufs + (size_t)(k & 1) * 16777216;

    s16x8 bf[4][KC];
    f32x4 bias4[4];
#pragma unroll
    for (int j = 0; j < 4; ++j) {
      const int n = w * 64 + j * 16 + l15;
      const unsigned short* wp = wihb + ((size_t)ed * 512 + n) * KS + lq * 8;
#pragma unroll
      for (int kc = 0; kc < KC; ++kc) bf[j][kc] = *(const s16x8*)(wp + kc * 32);
      bias4[j] = *(const f32x4*)(biasb + ed * 512 + w * 64 + j * 16 + lq * 4);
    }
    for (int ss = slice; ss < 64; ss += nsl) {
      const int s = k * 64 + ss;
      const int t = d ? 1023 - s : s;
#pragma unroll
      for (int mt = 0; mt < 2; ++mt) {
        const size_t arow = (size_t)(L ? (e * 1024 + t) : t) * 32 + mt * 16 + l15;
        const unsigned short* ap = Asrc + arow * KS + lq * 8;
        s16x8 af[KC];
#pragma unroll
        for (int kc = 0; kc < KC; ++kc) af[kc] = *(const s16x8*)(ap + kc * 32);
        f32x4 acc[4];
#pragma unroll
        for (int j = 0; j < 4; ++j) acc[j] = bias4[j];
#pragma unroll
        for (int kc = 0; kc < KC; ++kc) {
#pragma unroll
          for (int j = 0; j < 4; ++j) acc[j] = mfma16(bf[j][kc], af[kc], acc[j]);
        }
        // D'[n = w*64+j*16+lq*4+r][row = l15] -> xw[ed2mt][ss][row][n]
        unsigned short* op = xw + (((size_t)(ed * 2 + mt) * 64 + ss) * 16 + l15) * 512 + w * 64 + lq * 4;
#pragma unroll
        for (int j = 0; j < 4; ++j) {
          ushort4 o4;
          o4.x = f2bf(acc[j][0]); o4.y = f2bf(acc[j][1]);
          o4.z = f2bf(acc[j][2]); o4.w = f2bf(acc[j][3]);
          *(ushort4*)(op + j * 16) = o4;
        }
      }
    }
    return;
  }

  // ================= REC role: chunk c = k-1 (transposed scheme) ============
  const int c = k - 1;
  if (c < 0 || c > 15) return;
  __builtin_amdgcn_s_setprio(2);
  const int rb = blockIdx.x, ed2 = rb >> 1, bh = rb & 1;
  const int e = ed2 >> 1, d = ed2 & 1;
  __shared__ __align__(16) char hbf[2][4096];
  const int row = l15;                 // batch row within bh half
  const int cellb = w * 16 + lq * 4;   // base cell of this thread's gate quad

  // Whh A-fragments (identical loads to the old B-fragments)
  s16x8 bfh[4][4];
#pragma unroll
  for (int g = 0; g < 4; ++g) {
    const unsigned short* wp = whhb + ((size_t)ed2 * 512 + g * 128 + w * 16 + l15) * 128 + lq * 8;
#pragma unroll
    for (int kc = 0; kc < 4; ++kc) bfh[g][kc] = *(const s16x8*)(wp + kc * 32);
  }
  const int swz = (row & 7) << 4;
  const int wbyte = row * 256 + ((w * 32 + lq * 8) ^ swz);
  float cst[4];
  ushort4 hb4;
  if (c == 0) {
#pragma unroll
    for (int r = 0; r < 4; ++r) cst[r] = 0.f;
    hb4.x = 0; hb4.y = 0; hb4.z = 0; hb4.w = 0;
    if (tid < 256) {
      s16x8 z = {0,0,0,0,0,0,0,0};
      *(s16x8*)(&hbf[0][tid * 16]) = z;
    }
  } else {
    const float* cp = cstate + ((size_t)rb * 512 + tid) * 4;
    const unsigned short* hp = hstate + ((size_t)rb * 512 + tid) * 4;
#pragma unroll
    for (int r = 0; r < 4; ++r) cst[r] = cp[r];
    hb4 = *(const ushort4*)hp;
    *(ushort4*)(&hbf[0][wbyte]) = hb4;
  }
  __syncthreads();

  const unsigned short* xwp =
      xwbufs + (size_t)(c & 1) * 16777216 + ((size_t)(ed2 * 2 + bh) * 64) * 8192 + row * 512 + cellb;
  const int grow = bh * 16 + row;      // global batch row

  ushort4 xq[4];
#pragma unroll
  for (int g = 0; g < 4; ++g) xq[g] = *(const ushort4*)(xwp + g * 128);

  for (int tt = 0; tt < 64; ++tt) {
    const int p = tt & 1;
    // prefetch next step's xw
    ushort4 nxq[4];
    {
      const int tn = tt < 63 ? tt + 1 : 63;
#pragma unroll
      for (int g = 0; g < 4; ++g)
        nxq[g] = *(const ushort4*)(xwp + (size_t)tn * 8192 + g * 128);
    }
    // store previous step's h (one ushort4 from register carry)
    if (tt > 0) {
      const int ptt = tt - 1;
      size_t ob;
      if (L) {
        ob = (size_t)(c & 1) * 4194304 + (((size_t)e * 64 + ptt) * 32 + grow) * 256 + d * 128 + cellb;
      } else {
        const int s = c * 64 + ptt;
        const int tg = d ? 1023 - s : s;
        ob = (((size_t)e * 1024 + tg) * 32 + grow) * 256 + d * 128 + cellb;
      }
      *(ushort4*)(hout + ob) = hb4;
    }

    // h feedback fragments (B-operand): h[row][cells kc*32 + lq*8 ..+8]
    s16x8 hf[4];
#pragma unroll
    for (int kc = 0; kc < 4; ++kc)
      hf[kc] = *(const s16x8*)(&hbf[p][row * 256 + ((kc * 64 + lq * 16) ^ swz)]);

    // C-init from xw, split accumulation chains (kc 0-1 / 2-3)
    f32x4 aA[4], aB[4];
#pragma unroll
    for (int g = 0; g < 4; ++g) {
      aA[g][0] = bf2f(xq[g].x); aA[g][1] = bf2f(xq[g].y);
      aA[g][2] = bf2f(xq[g].z); aA[g][3] = bf2f(xq[g].w);
      aB[g] = f32x4{0.f, 0.f, 0.f, 0.f};
    }
#pragma unroll
    for (int g = 0; g < 4; ++g) {
      aA[g] = mfma16(bfh[g][0], hf[0], aA[g]);
      aB[g] = mfma16(bfh[g][2], hf[2], aB[g]);
    }
#pragma unroll
    for (int g = 0; g < 4; ++g) {
      aA[g] = mfma16(bfh[g][1], hf[1], aA[g]);
      aB[g] = mfma16(bfh[g][3], hf[3], aB[g]);
    }
#pragma unroll
    for (int g = 0; g < 4; ++g) aA[g] += aB[g];

    // gates (pre-scaled inputs; overflow-safe clamps) — r=cell offset now
    unsigned short hh[4];
#pragma unroll
    for (int r = 0; r < 4; ++r) {
      const float ai = ex2(aA[0][r]);
      const float af = ex2(aA[1][r]);
      const float bg = ex2(fminf(aA[2][r], 80.f));
      const float ao = ex2(aA[3][r]);
      const float sf = rcp_(1.f + af);
      const float r1 = rcp_((1.f + ai) * (1.f + bg));
      const float bgm = __builtin_fmaf(bg, K2L, -K2L);
      const float cc = __builtin_fmaf(sf, cst[r], bgm * r1);
      cst[r] = cc;
      const float qc = ex2(fminf(cc, 80.f));
      const float r2 = rcp_((1.f + ao) * (1.f + qc));
      hh[r] = f2bf((qc - 1.f) * r2);
    }
    hb4.x = hh[0]; hb4.y = hh[1]; hb4.z = hh[2]; hb4.w = hh[3];
    // h feedback write: single b64
    *(ushort4*)(&hbf[1 - p][wbyte]) = hb4;
    __syncthreads();
#pragma unroll
    for (int g = 0; g < 4; ++g) xq[g] = nxq[g];
  }

  // epilogue: store h(63) + carry state
  {
    size_t ob;
    if (L) {
      ob = (size_t)(c & 1) * 4194304 + (((size_t)e * 64 + 63) * 32 + grow) * 256 + d * 128 + cellb;
    } else {
      const int s = c * 64 + 63;
      const int tg = d ? 1023 - s : s;
      ob = (((size_t)e * 1024 + tg) * 32 + grow) * 256 + d * 128 + cellb;
    }
    *(ushort4*)(hout + ob) = hb4;
    unsigned short* hsp = hstate + ((size_t)rb * 512 + tid) * 4;
    float* csp = cstate + ((size_t)rb * 512 + tid) * 4;
    *(ushort4*)hsp = hb4;
#pragma unroll
    for (int r = 0; r < 4; ++r) csp[r] = cst[r];
  }
  __builtin_amdgcn_s_setprio(0);
}

// ---------------------------------------------------------------- launch
extern "C" void kernel_launch(void* const* d_in, const int* in_sizes, int n_in,
                              void* d_out, int out_size, void* d_ws, size_t ws_size,
                              hipStream_t stream) {
  const float* x    = (const float*)d_in[0];
  const float* spk  = (const float*)d_in[1];
  const float* wgw  = (const float*)d_in[2];
  const float* wgb  = (const float*)d_in[3];
  const float* Wih0 = (const float*)d_in[4];
  const float* Whh0 = (const float*)d_in[5];
  const float* bih0 = (const float*)d_in[6];
  const float* bhh0 = (const float*)d_in[7];
  const float* Wih1 = (const float*)d_in[8];
  const float* Whh1 = (const float*)d_in[9];
  const float* bih1 = (const float*)d_in[10];
  const float* bhh1 = (const float*)d_in[11];
  const float* fc1w = (const float*)d_in[12];
  const float* fc1b = (const float*)d_in[13];
  const float* fcw  = (const float*)d_in[14];
  const float* fcb  = (const float*)d_in[15];
  float* out = (float*)d_out;

  if (ws_size < (size_t)WS_NEED) {
    wsdbg_kernel<<<1, 1, 0, stream>>>(out, (float)(ws_size >> 20));
    return;
  }
  char* ws = (char*)d_ws;
  unsigned short* h0     = (unsigned short*)(ws + OFF_H0);
  unsigned short* xwbufs = (unsigned short*)(ws + OFF_XW);
  unsigned short* xt     = (unsigned short*)(ws + OFF_XT);
  unsigned short* whhb   = (unsigned short*)(ws + OFF_WHH);
  unsigned short* h1c    = (unsigned short*)(ws + OFF_H1C);
  unsigned short* hstate = (unsigned short*)(ws + OFF_HST);
  float*          cstate = (float*)(ws + OFF_CST);
  float*          Mmat   = (float*)(ws + OFF_M);
  float*          Cv     = (float*)(ws + OFF_CV);
  float*          gatesw = (float*)(ws + OFF_G);
  unsigned short* wihb0  = (unsigned short*)(ws + OFF_WIH0);
  unsigned short* wihb1  = (unsigned short*)(ws + OFF_WIH1);
  float*          biasb  = (float*)(ws + OFF_BIA);

  prep_kernel<<<4096, 512, 0, stream>>>(Whh0, Whh1, Wih0, Wih1, bih0, bhh0, bih1, bhh1,
                                        whhb, wihb0, wihb1, biasb);
  prepx_kernel<<<4096, 512, 0, stream>>>(x, xt);
  mprep_kernel<<<48, 256, 0, stream>>>(fc1w, fc1b, fcw, fcb, Mmat, Cv);
  initout_kernel<<<2816, 512, 0, stream>>>(Cv, out);
  gating_kernel<<<1, 256, 0, stream>>>(spk, wgw, wgb, gatesw, out + 1441792);

  for (int k = 0; k <= 16; ++k)
    fused<0><<<256, 512, 0, stream>>>(k, xt, wihb0, biasb, whhb, xwbufs,
                                      hstate, cstate, h0, nullptr, nullptr, out);
  for (int k = 0; k <= 17; ++k)
    fused<1><<<256, 512, 0, stream>>>(k, h0, wihb1, biasb + 8192, whhb + 1048576, xwbufs,
                                      hstate, cstate, h1c, Mmat, gatesw, out);
}

// Round 15
// 2183.535 us; speedup vs baseline: 1.5771x; 1.0284x over previous
//
#include <hip/hip_runtime.h>

typedef __attribute__((ext_vector_type(4))) float f32x4;
typedef __attribute__((ext_vector_type(8))) short s16x8;

#define LOG2E 1.4426950408889634f
#define K2L   2.8853900817779268f  /* 2*log2(e) */

__device__ __forceinline__ unsigned short f2bf(float f) {
  union { float f; unsigned int i; } v; v.f = f;
  unsigned int u = v.i;
  u = (u + 0x7FFFu + ((u >> 16) & 1u)) >> 16;
  return (unsigned short)u;
}
__device__ __forceinline__ float bf2f(unsigned short s) {
  union { unsigned int i; float f; } v; v.i = ((unsigned int)s) << 16;
  return v.f;
}
__device__ __forceinline__ float rcp_(float x) { return __builtin_amdgcn_rcpf(x); }
__device__ __forceinline__ float ex2(float x) { return __builtin_amdgcn_exp2f(x); }
__device__ __forceinline__ f32x4 mfma16(s16x8 a, s16x8 b, f32x4 c) {
  return __builtin_amdgcn_mfma_f32_16x16x32_bf16(a, b, c, 0, 0, 0);
}
__device__ __forceinline__ s16x8 pack8s(const float* s, float sc) {
  s16x8 v;
#pragma unroll
  for (int j = 0; j < 8; ++j) v[j] = (short)f2bf(s[j] * sc);
  return v;
}

// ws offsets (bytes)
#define OFF_H0   0            /* 134217728: h0 bf16 [8e][1024t][32b][256] */
#define OFF_XW   134217728    /* 67108864: 2 x 32MB xw ring */
#define OFF_XT   201326592    /* 8388608: xt bf16 [1024t][32b][128] */
#define OFF_WHH  209715200    /* 4194304: whhb bf16 (pre-scaled) */
#define OFF_H1C  213909504    /* 16777216: 2 x 8MB h1 chunk [8e][64ss][32b][256] */
#define OFF_HST  230686720    /* 131072 */
#define OFF_CST  230817792    /* 262144 */
#define OFF_M    231079936    /* 49152: M f32 [2][48][128] */
#define OFF_CV   231129088    /* 256 */
#define OFF_G    231129344    /* 1024 */
#define OFF_WIH0 231130368    /* 2097152: wihb0 bf16 [16ed][512n][128k] pre-scaled */
#define OFF_WIH1 233227520    /* 4194304: wihb1 bf16 [16ed][512n][256k] pre-scaled */
#define OFF_BIA  237421824    /* 131072: biasb f32 [2L][16ed][512] pre-scaled */
#define WS_NEED  237552896

// ---------------------------------------------------------------- ws diag
__global__ void wsdbg_kernel(float* __restrict__ out, float v) { out[0] = v; }

// ---------------------------------------------------------------- prep: pre-scaled bf16 weights + biases
__global__ void prep_kernel(const float* __restrict__ Whh0, const float* __restrict__ Whh1,
                            const float* __restrict__ Wih0, const float* __restrict__ Wih1,
                            const float* __restrict__ bih0, const float* __restrict__ bhh0,
                            const float* __restrict__ bih1, const float* __restrict__ bhh1,
                            unsigned short* __restrict__ whhb,
                            unsigned short* __restrict__ wihb0,
                            unsigned short* __restrict__ wihb1,
                            float* __restrict__ biasb) {
  const int tid = blockIdx.x * 512 + threadIdx.x;  // 2,097,152 threads
  for (int i = tid; i < 5242880; i += 2097152) {
    if (i < 2097152) {
      const int gate = (i >> 14) & 3;
      const float sc = (gate == 2) ? K2L : -LOG2E;
      whhb[i] = f2bf((i < 1048576 ? Whh0[i] : Whh1[i - 1048576]) * sc);
    } else if (i < 3145728) {
      const int j = i - 2097152;
      const int gate = (j >> 14) & 3;  // k=128
      const float sc = (gate == 2) ? K2L : -LOG2E;
      wihb0[j] = f2bf(Wih0[j] * sc);
    } else {
      const int j = i - 3145728;
      const int gate = (j >> 15) & 3;  // k=256
      const float sc = (gate == 2) ? K2L : -LOG2E;
      wihb1[j] = f2bf(Wih1[j] * sc);
    }
  }
  if (tid < 16384) {
    const int L = tid >> 13, rem = tid & 8191;
    const int gate = (rem >> 7) & 3;
    const float sc = (gate == 2) ? K2L : -LOG2E;
    const float b = L ? (bih1[rem] + bhh1[rem]) : (bih0[rem] + bhh0[rem]);
    biasb[tid] = b * sc;
  }
}

// ---------------------------------------------------------------- prep: x -> xt bf16 [t][b][128]
__global__ void prepx_kernel(const float* __restrict__ x, unsigned short* __restrict__ xt) {
  const int i = blockIdx.x * 512 + threadIdx.x;
  for (int j = i; j < 4194304; j += 2097152) {
    const int b = j >> 17, rem = j & 131071, t = rem >> 7, f = rem & 127;
    xt[((size_t)t * 32 + b) * 128 + f] = f2bf(x[j]);
  }
}

// ---------------------------------------------------------------- prep: M = fc_w @ fc1_w halves; Cv = fc_w@fc1_b + fc_b
__global__ void mprep_kernel(const float* __restrict__ fc1w, const float* __restrict__ fc1b,
                             const float* __restrict__ fcw, const float* __restrict__ fcb,
                             float* __restrict__ M, float* __restrict__ Cv) {
  const int mi = blockIdx.x * 256 + threadIdx.x;  // grid 48
  if (mi < 12288) {  // [2][48][128]
    const int dd = mi / 6144, rem = mi % 6144, o = rem >> 7, hc = rem & 127;
    float s = 0.f;
    if (o < 44)
      for (int h = 0; h < 128; ++h) s += fcw[o * 128 + h] * fc1w[h * 256 + dd * 128 + hc];
    M[mi] = s;
  }
  if (blockIdx.x == 0 && threadIdx.x < 44) {
    const int o = threadIdx.x;
    float s = fcb[o];
    for (int h = 0; h < 128; ++h) s += fcw[o * 128 + h] * fc1b[h];
    Cv[o] = s;
  }
}

// ---------------------------------------------------------------- out init: out[t,b,o] = Cv[o]
__global__ void initout_kernel(const float* __restrict__ Cv, float* __restrict__ out) {
  const int i = blockIdx.x * 512 + threadIdx.x;
  if (i < 1441792) out[i] = Cv[i % 44];
}

// ---------------------------------------------------------------- gating: gates + loss
__global__ void gating_kernel(const float* __restrict__ spk,
                              const float* __restrict__ wgw,
                              const float* __restrict__ wgb,
                              float* __restrict__ gates_out,
                              float* __restrict__ loss_out) {
  __shared__ __align__(16) float logits[32][8];
  __shared__ __align__(16) float gmat[32][8];
  const int tid = threadIdx.x;
  {
    const int b = tid >> 3, e = tid & 7;
    float s = wgb[e];
    for (int k = 0; k < 256; ++k) s += spk[b * 256 + k] * wgw[e * 256 + k];
    logits[b][e] = s;
  }
  __syncthreads();
  if (tid < 32) {
    const int b = tid;
    float v[8];
    for (int e = 0; e < 8; ++e) v[e] = logits[b][e];
    int idx[4]; float val[4];
    unsigned used = 0;
    for (int k = 0; k < 4; ++k) {
      float best = -1e30f; int bi = 0;
      for (int e = 0; e < 8; ++e)
        if (!((used >> e) & 1) && v[e] > best) { best = v[e]; bi = e; }
      used |= (1u << bi); idx[k] = bi; val[k] = best;
    }
    const float m = val[0];
    float ex[4], ssum = 0.f;
    for (int k = 0; k < 4; ++k) { ex[k] = ex2(LOG2E * (val[k] - m)); ssum += ex[k]; }
    for (int e = 0; e < 8; ++e) gmat[b][e] = 0.f;
    for (int k = 0; k < 4; ++k) gmat[b][idx[k]] = ex[k] / ssum;
    for (int e = 0; e < 8; ++e) gates_out[b * 8 + e] = gmat[b][e];
  }
  __syncthreads();
  if (tid == 0) {
    float imp[8], ld[8];
    for (int e = 0; e < 8; ++e) {
      float si = 0.f, sl = 0.f;
      for (int b = 0; b < 32; ++b) { si += gmat[b][e]; sl += (gmat[b][e] > 0.f) ? 1.f : 0.f; }
      imp[e] = si; ld[e] = sl;
    }
    float mi = 0.f, ml = 0.f;
    for (int e = 0; e < 8; ++e) { mi += imp[e]; ml += ld[e]; }
    mi *= 0.125f; ml *= 0.125f;
    float vi = 0.f, vl = 0.f;
    for (int e = 0; e < 8; ++e) {
      vi += (imp[e] - mi) * (imp[e] - mi);
      vl += (ld[e] - ml) * (ld[e] - ml);
    }
    vi /= 7.f; vl /= 7.f;
    loss_out[0] = 0.01f * (vi / (mi * mi + 1e-10f) + vl / (ml * ml + 1e-10f));
  }
}

// ---------------------------------------------------------------- fused: gemm (chunk k) | rec (k-1) | fold (k-2, L1)
// xw: ushort [ed2*2+bh][64 ss][512 n][16 b]; n = gate*128 + cell (pre-scaled values).
// LDS h slot: (cell,b) at byte (cell>>5)<<10 | ((cell>>3)&3)<<8 | b<<4 | (cell&7)<<1.
// h0: [e][1024 t][32 b][256];  h1 chunk ring: [e][64 ss][32 b][256] x2.
// Rec step: hf ds_read issued FIRST after barrier (latency overlaps prefetch/store
// issue); MFMA accumulation split 2+2 (aA: kc0/1 + xw C-init, aB: kc2/3).
template <int L>
__global__ __launch_bounds__(512, 1) void fused(
    int k,
    const unsigned short* __restrict__ Asrc,
    const unsigned short* __restrict__ wihb,
    const float* __restrict__ biasb,
    const unsigned short* __restrict__ whhb,
    unsigned short* __restrict__ xwbufs,
    unsigned short* __restrict__ hstate, float* __restrict__ cstate,
    unsigned short* __restrict__ hout,
    const float* __restrict__ Mmat, const float* __restrict__ gatesp,
    float* __restrict__ outp) {
  constexpr int KC = L ? 8 : 4;
  constexpr int KS = KC * 32;
  const int tid = threadIdx.x, w = tid >> 6, l = tid & 63;
  const int l15 = l & 15, lq = l >> 4;

  if (L && blockIdx.x >= 192) {
    // ================= FOLD role: chunk c2 = k-2 =================
    const int c2 = k - 2;
    if (c2 < 0 || c2 > 15) return;
    if (w >= 6) return;
    const int ss = blockIdx.x - 192;
    const int mt = (w >= 3) ? 1 : 0, ot = w - mt * 3;
    const int o = ot * 16 + l15;
    const bool ov = o < 44;
    s16x8 bfm[2][4];
#pragma unroll
    for (int dd = 0; dd < 2; ++dd)
#pragma unroll
      for (int kc = 0; kc < 4; ++kc) {
        if (ov) bfm[dd][kc] = pack8s(Mmat + ((size_t)dd * 48 + o) * 128 + kc * 32 + lq * 8, 1.f);
        else { s16x8 z = {0,0,0,0,0,0,0,0}; bfm[dd][kc] = z; }
      }
    const unsigned short* hb = hout + (size_t)(c2 & 1) * 4194304;
    f32x4 acc0 = {0.f,0.f,0.f,0.f}, acc1 = {0.f,0.f,0.f,0.f};
    for (int e = 0; e < 8; ++e) {
      const unsigned short* ap = hb + ((((size_t)e * 64 + ss) * 32) + mt * 16 + l15) * 256 + lq * 8;
      f32x4 p0 = {0.f,0.f,0.f,0.f}, p1 = {0.f,0.f,0.f,0.f};
#pragma unroll
      for (int kc = 0; kc < 4; ++kc) {
        s16x8 a0 = *(const s16x8*)(ap + kc * 32);
        s16x8 a1 = *(const s16x8*)(ap + 128 + kc * 32);
        p0 = mfma16(a0, bfm[0][kc], p0);
        p1 = mfma16(a1, bfm[1][kc], p1);
      }
#pragma unroll
      for (int r = 0; r < 4; ++r) {
        const float g = gatesp[(mt * 16 + lq * 4 + r) * 8 + e];
        acc0[r] += g * p0[r];
        acc1[r] += g * p1[r];
      }
    }
    if (ov) {
      const int s2 = c2 * 64 + ss, t1 = 1023 - s2;
#pragma unroll
      for (int r = 0; r < 4; ++r) {
        const int b = mt * 16 + lq * 4 + r;
        outp[((size_t)s2 * 32 + b) * 44 + o] += acc0[r];
        outp[((size_t)t1 * 32 + b) * 44 + o] += acc1[r];
      }
    }
    return;
  }

  if (blockIdx.x >= 32) {
    // ================= GEMM role: xw chunk k (prepacked weights) =================
    if (k >= 16) return;
    const int gb = blockIdx.x - 32;
    const int ed = gb & 15, e = ed >> 1, d = ed & 1;
    const int slice = gb >> 4;
    const int nsl = L ? 10 : 14;
    unsigned short* xw = xwbufs + (size_t)(k & 1) * 16777216;

    s16x8 bf[4][KC];
    float bias[4];
#pragma unroll
    for (int j = 0; j < 4; ++j) {
      const int n = w * 64 + j * 16 + l15;
      bias[j] = biasb[ed * 512 + n];
      const unsigned short* wp = wihb + ((size_t)ed * 512 + n) * KS + lq * 8;
#pragma unroll
      for (int kc = 0; kc < KC; ++kc) bf[j][kc] = *(const s16x8*)(wp + kc * 32);
    }
    for (int ss = slice; ss < 64; ss += nsl) {
      const int s = k * 64 + ss;
      const int t = d ? 1023 - s : s;
#pragma unroll
      for (int mt = 0; mt < 2; ++mt) {
        const size_t arow = (size_t)(L ? (e * 1024 + t) : t) * 32 + mt * 16 + l15;
        const unsigned short* ap = Asrc + arow * KS + lq * 8;
        s16x8 af[KC];
#pragma unroll
        for (int kc = 0; kc < KC; ++kc) af[kc] = *(const s16x8*)(ap + kc * 32);
        f32x4 acc[4];
#pragma unroll
        for (int j = 0; j < 4; ++j) acc[j] = f32x4{bias[j], bias[j], bias[j], bias[j]};
#pragma unroll
        for (int kc = 0; kc < KC; ++kc) {
#pragma unroll
          for (int j = 0; j < 4; ++j) acc[j] = mfma16(af[kc], bf[j][kc], acc[j]);
        }
        unsigned short* op = xw + (((size_t)(ed * 2 + mt) * 64 + ss) * 512) * 16 + lq * 4;
#pragma unroll
        for (int j = 0; j < 4; ++j) {
          const int n = w * 64 + j * 16 + l15;
          ushort4 o4;
          o4.x = f2bf(acc[j][0]); o4.y = f2bf(acc[j][1]);
          o4.z = f2bf(acc[j][2]); o4.w = f2bf(acc[j][3]);
          *(ushort4*)(op + (size_t)n * 16) = o4;
        }
      }
    }
    return;
  }

  // ================= REC role: chunk c = k-1 =================
  const int c = k - 1;
  if (c < 0 || c > 15) return;
  __builtin_amdgcn_s_setprio(2);
  const int rb = blockIdx.x, ed2 = rb >> 1, bh = rb & 1;
  const int e = ed2 >> 1, d = ed2 & 1;
  __shared__ __align__(16) char hbf[2][4096];
  const int cell = w * 16 + l15;

  s16x8 bfh[4][4];  // pre-scaled Whh
#pragma unroll
  for (int g = 0; g < 4; ++g) {
    const unsigned short* wp = whhb + ((size_t)ed2 * 512 + g * 128 + cell) * 128 + lq * 8;
#pragma unroll
    for (int kc = 0; kc < 4; ++kc) bfh[g][kc] = *(const s16x8*)(wp + kc * 32);
  }
  const int wb0 = ((cell >> 5) << 10) | (((cell >> 3) & 3) << 8) | ((cell & 7) << 1);
  float cst[4];
  unsigned short hb4[4];
  if (c == 0) {
#pragma unroll
    for (int r = 0; r < 4; ++r) { cst[r] = 0.f; hb4[r] = 0; }
    if (tid < 256) {
      s16x8 z = {0,0,0,0,0,0,0,0};
      *(s16x8*)(&hbf[0][tid * 16]) = z;
    }
  } else {
    const float* cp = cstate + ((size_t)rb * 512 + tid) * 4;
    const unsigned short* hp = hstate + ((size_t)rb * 512 + tid) * 4;
#pragma unroll
    for (int r = 0; r < 4; ++r) {
      cst[r] = cp[r];
      hb4[r] = hp[r];
      *(unsigned short*)(&hbf[0][wb0 | ((lq * 4 + r) << 4)]) = hp[r];
    }
  }
  __syncthreads();

  const unsigned short* xwb =
      xwbufs + (size_t)(c & 1) * 16777216 + ((size_t)(ed2 * 2 + bh) * 64) * 8192 + cell * 16 + lq * 4;
  const int brow = bh * 16 + lq * 4;

  ushort4 xq[4];
#pragma unroll
  for (int g = 0; g < 4; ++g) xq[g] = *(const ushort4*)(xwb + g * 2048);

  for (int tt = 0; tt < 64; ++tt) {
    const int p = tt & 1;
    // 1. h feedback fragments FIRST: start the ds_read latency immediately
    //    after the barrier; prefetch/store issue hides under it.
    s16x8 hf[4];
#pragma unroll
    for (int kc = 0; kc < 4; ++kc) hf[kc] = *(const s16x8*)(&hbf[p][kc * 1024 + l * 16]);
    // 2. prefetch next xw
    ushort4 nxq[4];
    {
      const int tn = tt < 63 ? tt + 1 : 63;
#pragma unroll
      for (int g = 0; g < 4; ++g) nxq[g] = *(const ushort4*)(xwb + (size_t)tn * 8192 + g * 2048);
    }
    // 3. store previous step's h from register carry
    if (tt > 0) {
      const int ptt = tt - 1;
      size_t ob;
      if (L) {
        ob = (size_t)(c & 1) * 4194304 + (((size_t)e * 64 + ptt) * 32 + brow) * 256 + d * 128 + cell;
      } else {
        const int s = c * 64 + ptt;
        const int tg = d ? 1023 - s : s;
        ob = (((size_t)e * 1024 + tg) * 32 + brow) * 256 + d * 128 + cell;
      }
#pragma unroll
      for (int r = 0; r < 4; ++r) hout[ob + (size_t)r * 256] = hb4[r];
    }
    // 4. unpack xw pre-activations into aA; aB accumulates kc2/3 from zero
    f32x4 aA[4], aB[4];
#pragma unroll
    for (int g = 0; g < 4; ++g) {
      aA[g][0] = bf2f(xq[g].x); aA[g][1] = bf2f(xq[g].y);
      aA[g][2] = bf2f(xq[g].z); aA[g][3] = bf2f(xq[g].w);
      aB[g] = f32x4{0.f, 0.f, 0.f, 0.f};
    }
    // 5. recurrent MFMA, 2+2 split chains
#pragma unroll
    for (int g = 0; g < 4; ++g) {
      aA[g] = mfma16(hf[0], bfh[g][0], aA[g]);
      aB[g] = mfma16(hf[2], bfh[g][2], aB[g]);
    }
#pragma unroll
    for (int g = 0; g < 4; ++g) {
      aA[g] = mfma16(hf[1], bfh[g][1], aA[g]);
      aB[g] = mfma16(hf[3], bfh[g][3], aB[g]);
    }
#pragma unroll
    for (int g = 0; g < 4; ++g) aA[g] += aB[g];

    // 6. gates (pre-scaled inputs; overflow-safe clamps)
#pragma unroll
    for (int r = 0; r < 4; ++r) {
      const float ai = ex2(aA[0][r]);
      const float af = ex2(aA[1][r]);
      const float bg = ex2(fminf(aA[2][r], 80.f));
      const float ao = ex2(aA[3][r]);
      const float sf = rcp_(1.f + af);
      const float r1 = rcp_((1.f + ai) * (1.f + bg));
      const float bgm = __builtin_fmaf(bg, K2L, -K2L);
      const float cc = __builtin_fmaf(sf, cst[r], bgm * r1);
      cst[r] = cc;
      const float qc = ex2(fminf(cc, 80.f));
      const float r2 = rcp_((1.f + ao) * (1.f + qc));
      hb4[r] = f2bf((qc - 1.f) * r2);
    }
    // 7. h feedback write (other buffer)
    char* hw = &hbf[1 - p][0];
#pragma unroll
    for (int r = 0; r < 4; ++r)
      *(unsigned short*)(hw + (wb0 | ((lq * 4 + r) << 4))) = hb4[r];
    __syncthreads();
#pragma unroll
    for (int g = 0; g < 4; ++g) xq[g] = nxq[g];
  }

  // epilogue: store h(63) + carry state
  {
    size_t ob;
    if (L) {
      ob = (size_t)(c & 1) * 4194304 + (((size_t)e * 64 + 63) * 32 + brow) * 256 + d * 128 + cell;
    } else {
      const int s = c * 64 + 63;
      const int tg = d ? 1023 - s : s;
      ob = (((size_t)e * 1024 + tg) * 32 + brow) * 256 + d * 128 + cell;
    }
#pragma unroll
    for (int r = 0; r < 4; ++r) hout[ob + (size_t)r * 256] = hb4[r];
    unsigned short* hsp = hstate + ((size_t)rb * 512 + tid) * 4;
    float* csp = cstate + ((size_t)rb * 512 + tid) * 4;
#pragma unroll
    for (int r = 0; r < 4; ++r) { hsp[r] = hb4[r]; csp[r] = cst[r]; }
  }
  __builtin_amdgcn_s_setprio(0);
}

// ---------------------------------------------------------------- launch
extern "C" void kernel_launch(void* const* d_in, const int* in_sizes, int n_in,
                              void* d_out, int out_size, void* d_ws, size_t ws_size,
                              hipStream_t stream) {
  const float* x    = (const float*)d_in[0];
  const float* spk  = (const float*)d_in[1];
  const float* wgw  = (const float*)d_in[2];
  const float* wgb  = (const float*)d_in[3];
  const float* Wih0 = (const float*)d_in[4];
  const float* Whh0 = (const float*)d_in[5];
  const float* bih0 = (const float*)d_in[6];
  const float* bhh0 = (const float*)d_in[7];
  const float* Wih1 = (const float*)d_in[8];
  const float* Whh1 = (const float*)d_in[9];
  const float* bih1 = (const float*)d_in[10];
  const float* bhh1 = (const float*)d_in[11];
  const float* fc1w = (const float*)d_in[12];
  const float* fc1b = (const float*)d_in[13];
  const float* fcw  = (const float*)d_in[14];
  const float* fcb  = (const float*)d_in[15];
  float* out = (float*)d_out;

  if (ws_size < (size_t)WS_NEED) {
    wsdbg_kernel<<<1, 1, 0, stream>>>(out, (float)(ws_size >> 20));
    return;
  }
  char* ws = (char*)d_ws;
  unsigned short* h0     = (unsigned short*)(ws + OFF_H0);
  unsigned short* xwbufs = (unsigned short*)(ws + OFF_XW);
  unsigned short* xt     = (unsigned short*)(ws + OFF_XT);
  unsigned short* whhb   = (unsigned short*)(ws + OFF_WHH);
  unsigned short* h1c    = (unsigned short*)(ws + OFF_H1C);
  unsigned short* hstate = (unsigned short*)(ws + OFF_HST);
  float*          cstate = (float*)(ws + OFF_CST);
  float*          Mmat   = (float*)(ws + OFF_M);
  float*          Cv     = (float*)(ws + OFF_CV);
  float*          gatesw = (float*)(ws + OFF_G);
  unsigned short* wihb0  = (unsigned short*)(ws + OFF_WIH0);
  unsigned short* wihb1  = (unsigned short*)(ws + OFF_WIH1);
  float*          biasb  = (float*)(ws + OFF_BIA);

  prep_kernel<<<4096, 512, 0, stream>>>(Whh0, Whh1, Wih0, Wih1, bih0, bhh0, bih1, bhh1,
                                        whhb, wihb0, wihb1, biasb);
  prepx_kernel<<<4096, 512, 0, stream>>>(x, xt);
  mprep_kernel<<<48, 256, 0, stream>>>(fc1w, fc1b, fcw, fcb, Mmat, Cv);
  initout_kernel<<<2816, 512, 0, stream>>>(Cv, out);
  gating_kernel<<<1, 256, 0, stream>>>(spk, wgw, wgb, gatesw, out + 1441792);

  for (int k = 0; k <= 16; ++k)
    fused<0><<<256, 512, 0, stream>>>(k, xt, wihb0, biasb, whhb, xwbufs,
                                      hstate, cstate, h0, nullptr, nullptr, out);
  for (int k = 0; k <= 17; ++k)
    fused<1><<<256, 512, 0, stream>>>(k, h0, wihb1, biasb + 8192, whhb + 1048576, xwbufs,
                                      hstate, cstate, h1c, Mmat, gatesw, out);
}

// Round 16
// 2059.484 us; speedup vs baseline: 1.6721x; 1.0602x over previous
//
#include <hip/hip_runtime.h>

typedef __attribute__((ext_vector_type(4))) float f32x4;
typedef __attribute__((ext_vector_type(8))) short s16x8;

#define LOG2E 1.4426950408889634f
#define K2L   2.8853900817779268f  /* 2*log2(e) */

__device__ __forceinline__ unsigned short f2bf(float f) {
  union { float f; unsigned int i; } v; v.f = f;
  unsigned int u = v.i;
  u = (u + 0x7FFFu + ((u >> 16) & 1u)) >> 16;
  return (unsigned short)u;
}
__device__ __forceinline__ float bf2f(unsigned short s) {
  union { unsigned int i; float f; } v; v.i = ((unsigned int)s) << 16;
  return v.f;
}
__device__ __forceinline__ float rcp_(float x) { return __builtin_amdgcn_rcpf(x); }
__device__ __forceinline__ float ex2(float x) { return __builtin_amdgcn_exp2f(x); }
__device__ __forceinline__ f32x4 mfma16(s16x8 a, s16x8 b, f32x4 c) {
  return __builtin_amdgcn_mfma_f32_16x16x32_bf16(a, b, c, 0, 0, 0);
}
__device__ __forceinline__ s16x8 pack8s(const float* s, float sc) {
  s16x8 v;
#pragma unroll
  for (int j = 0; j < 8; ++j) v[j] = (short)f2bf(s[j] * sc);
  return v;
}

// ws offsets (bytes)
#define OFF_H0   0            /* 134217728: h0 bf16 [8e][1024t][32b][256] */
#define OFF_XW   134217728    /* 67108864: 2 x 32MB xw ring */
#define OFF_XT   201326592    /* 8388608: xt bf16 [1024t][32b][128] */
#define OFF_WHH  209715200    /* 4194304: whhb bf16 (pre-scaled) */
#define OFF_H1C  213909504    /* 16777216: 2 x 8MB h1 chunk [8e][64ss][32b][256] */
#define OFF_HST  230686720    /* 131072 */
#define OFF_CST  230817792    /* 262144 */
#define OFF_M    231079936    /* 49152: M f32 [2][48][128] */
#define OFF_CV   231129088    /* 256 */
#define OFF_G    231129344    /* 1024 */
#define OFF_WIH0 231130368    /* 2097152: wihb0 bf16 [16ed][512n][128k] pre-scaled */
#define OFF_WIH1 233227520    /* 4194304: wihb1 bf16 [16ed][512n][256k] pre-scaled */
#define OFF_BIA  237421824    /* 131072: biasb f32 [2L][16ed][512] pre-scaled */
#define WS_NEED  237552896

// ---------------------------------------------------------------- ws diag
__global__ void wsdbg_kernel(float* __restrict__ out, float v) { out[0] = v; }

// ---------------------------------------------------------------- prep: pre-scaled bf16 weights + biases
__global__ void prep_kernel(const float* __restrict__ Whh0, const float* __restrict__ Whh1,
                            const float* __restrict__ Wih0, const float* __restrict__ Wih1,
                            const float* __restrict__ bih0, const float* __restrict__ bhh0,
                            const float* __restrict__ bih1, const float* __restrict__ bhh1,
                            unsigned short* __restrict__ whhb,
                            unsigned short* __restrict__ wihb0,
                            unsigned short* __restrict__ wihb1,
                            float* __restrict__ biasb) {
  const int tid = blockIdx.x * 512 + threadIdx.x;  // 2,097,152 threads
  for (int i = tid; i < 5242880; i += 2097152) {
    if (i < 2097152) {
      const int gate = (i >> 14) & 3;
      const float sc = (gate == 2) ? K2L : -LOG2E;
      whhb[i] = f2bf((i < 1048576 ? Whh0[i] : Whh1[i - 1048576]) * sc);
    } else if (i < 3145728) {
      const int j = i - 2097152;
      const int gate = (j >> 14) & 3;  // k=128
      const float sc = (gate == 2) ? K2L : -LOG2E;
      wihb0[j] = f2bf(Wih0[j] * sc);
    } else {
      const int j = i - 3145728;
      const int gate = (j >> 15) & 3;  // k=256
      const float sc = (gate == 2) ? K2L : -LOG2E;
      wihb1[j] = f2bf(Wih1[j] * sc);
    }
  }
  if (tid < 16384) {
    const int L = tid >> 13, rem = tid & 8191;
    const int gate = (rem >> 7) & 3;
    const float sc = (gate == 2) ? K2L : -LOG2E;
    const float b = L ? (bih1[rem] + bhh1[rem]) : (bih0[rem] + bhh0[rem]);
    biasb[tid] = b * sc;
  }
}

// ---------------------------------------------------------------- prep: x -> xt bf16 [t][b][128]
__global__ void prepx_kernel(const float* __restrict__ x, unsigned short* __restrict__ xt) {
  const int i = blockIdx.x * 512 + threadIdx.x;
  for (int j = i; j < 4194304; j += 2097152) {
    const int b = j >> 17, rem = j & 131071, t = rem >> 7, f = rem & 127;
    xt[((size_t)t * 32 + b) * 128 + f] = f2bf(x[j]);
  }
}

// ---------------------------------------------------------------- prep: M = fc_w @ fc1_w halves; Cv = fc_w@fc1_b + fc_b
__global__ void mprep_kernel(const float* __restrict__ fc1w, const float* __restrict__ fc1b,
                             const float* __restrict__ fcw, const float* __restrict__ fcb,
                             float* __restrict__ M, float* __restrict__ Cv) {
  const int mi = blockIdx.x * 256 + threadIdx.x;  // grid 48
  if (mi < 12288) {  // [2][48][128]
    const int dd = mi / 6144, rem = mi % 6144, o = rem >> 7, hc = rem & 127;
    float s = 0.f;
    if (o < 44)
      for (int h = 0; h < 128; ++h) s += fcw[o * 128 + h] * fc1w[h * 256 + dd * 128 + hc];
    M[mi] = s;
  }
  if (blockIdx.x == 0 && threadIdx.x < 44) {
    const int o = threadIdx.x;
    float s = fcb[o];
    for (int h = 0; h < 128; ++h) s += fcw[o * 128 + h] * fc1b[h];
    Cv[o] = s;
  }
}

// ---------------------------------------------------------------- out init: out[t,b,o] = Cv[o]
__global__ void initout_kernel(const float* __restrict__ Cv, float* __restrict__ out) {
  const int i = blockIdx.x * 512 + threadIdx.x;
  if (i < 1441792) out[i] = Cv[i % 44];
}

// ---------------------------------------------------------------- gating: gates + loss
__global__ void gating_kernel(const float* __restrict__ spk,
                              const float* __restrict__ wgw,
                              const float* __restrict__ wgb,
                              float* __restrict__ gates_out,
                              float* __restrict__ loss_out) {
  __shared__ __align__(16) float logits[32][8];
  __shared__ __align__(16) float gmat[32][8];
  const int tid = threadIdx.x;
  {
    const int b = tid >> 3, e = tid & 7;
    float s = wgb[e];
    for (int k = 0; k < 256; ++k) s += spk[b * 256 + k] * wgw[e * 256 + k];
    logits[b][e] = s;
  }
  __syncthreads();
  if (tid < 32) {
    const int b = tid;
    float v[8];
    for (int e = 0; e < 8; ++e) v[e] = logits[b][e];
    int idx[4]; float val[4];
    unsigned used = 0;
    for (int k = 0; k < 4; ++k) {
      float best = -1e30f; int bi = 0;
      for (int e = 0; e < 8; ++e)
        if (!((used >> e) & 1) && v[e] > best) { best = v[e]; bi = e; }
      used |= (1u << bi); idx[k] = bi; val[k] = best;
    }
    const float m = val[0];
    float ex[4], ssum = 0.f;
    for (int k = 0; k < 4; ++k) { ex[k] = ex2(LOG2E * (val[k] - m)); ssum += ex[k]; }
    for (int e = 0; e < 8; ++e) gmat[b][e] = 0.f;
    for (int k = 0; k < 4; ++k) gmat[b][idx[k]] = ex[k] / ssum;
    for (int e = 0; e < 8; ++e) gates_out[b * 8 + e] = gmat[b][e];
  }
  __syncthreads();
  if (tid == 0) {
    float imp[8], ld[8];
    for (int e = 0; e < 8; ++e) {
      float si = 0.f, sl = 0.f;
      for (int b = 0; b < 32; ++b) { si += gmat[b][e]; sl += (gmat[b][e] > 0.f) ? 1.f : 0.f; }
      imp[e] = si; ld[e] = sl;
    }
    float mi = 0.f, ml = 0.f;
    for (int e = 0; e < 8; ++e) { mi += imp[e]; ml += ld[e]; }
    mi *= 0.125f; ml *= 0.125f;
    float vi = 0.f, vl = 0.f;
    for (int e = 0; e < 8; ++e) {
      vi += (imp[e] - mi) * (imp[e] - mi);
      vl += (ld[e] - ml) * (ld[e] - ml);
    }
    vi /= 7.f; vl /= 7.f;
    loss_out[0] = 0.01f * (vi / (mi * mi + 1e-10f) + vl / (ml * ml + 1e-10f));
  }
}

// ---------------------------------------------------------------- fused: gemm (chunk k) | rec (k-1) | fold (k-2, L1)
// xw: ushort [ed2*2+bh][64 ss][512 n][16 b]; n = gate*128 + cell (pre-scaled values).
// LDS h slot: (cell,b) at byte (cell>>5)<<10 | ((cell>>3)&3)<<8 | b<<4 | (cell&7)<<1.
// h0: [e][1024 t][32 b][256];  h1 chunk ring: [e][64 ss][32 b][256] x2.
// Rec waves run at s_setprio(2) so co-resident gemm waves don't steal issue (T5).
template <int L>
__global__ __launch_bounds__(512, 1) void fused(
    int k,
    const unsigned short* __restrict__ Asrc,
    const unsigned short* __restrict__ wihb,
    const float* __restrict__ biasb,
    const unsigned short* __restrict__ whhb,
    unsigned short* __restrict__ xwbufs,
    unsigned short* __restrict__ hstate, float* __restrict__ cstate,
    unsigned short* __restrict__ hout,
    const float* __restrict__ Mmat, const float* __restrict__ gatesp,
    float* __restrict__ outp) {
  constexpr int KC = L ? 8 : 4;
  constexpr int KS = KC * 32;
  const int tid = threadIdx.x, w = tid >> 6, l = tid & 63;
  const int l15 = l & 15, lq = l >> 4;

  if (L && blockIdx.x >= 192) {
    // ================= FOLD role: chunk c2 = k-2 =================
    const int c2 = k - 2;
    if (c2 < 0 || c2 > 15) return;
    if (w >= 6) return;
    const int ss = blockIdx.x - 192;
    const int mt = (w >= 3) ? 1 : 0, ot = w - mt * 3;
    const int o = ot * 16 + l15;
    const bool ov = o < 44;
    s16x8 bfm[2][4];
#pragma unroll
    for (int dd = 0; dd < 2; ++dd)
#pragma unroll
      for (int kc = 0; kc < 4; ++kc) {
        if (ov) bfm[dd][kc] = pack8s(Mmat + ((size_t)dd * 48 + o) * 128 + kc * 32 + lq * 8, 1.f);
        else { s16x8 z = {0,0,0,0,0,0,0,0}; bfm[dd][kc] = z; }
      }
    const unsigned short* hb = hout + (size_t)(c2 & 1) * 4194304;
    f32x4 acc0 = {0.f,0.f,0.f,0.f}, acc1 = {0.f,0.f,0.f,0.f};
    for (int e = 0; e < 8; ++e) {
      const unsigned short* ap = hb + ((((size_t)e * 64 + ss) * 32) + mt * 16 + l15) * 256 + lq * 8;
      f32x4 p0 = {0.f,0.f,0.f,0.f}, p1 = {0.f,0.f,0.f,0.f};
#pragma unroll
      for (int kc = 0; kc < 4; ++kc) {
        s16x8 a0 = *(const s16x8*)(ap + kc * 32);
        s16x8 a1 = *(const s16x8*)(ap + 128 + kc * 32);
        p0 = mfma16(a0, bfm[0][kc], p0);
        p1 = mfma16(a1, bfm[1][kc], p1);
      }
#pragma unroll
      for (int r = 0; r < 4; ++r) {
        const float g = gatesp[(mt * 16 + lq * 4 + r) * 8 + e];
        acc0[r] += g * p0[r];
        acc1[r] += g * p1[r];
      }
    }
    if (ov) {
      const int s2 = c2 * 64 + ss, t1 = 1023 - s2;
#pragma unroll
      for (int r = 0; r < 4; ++r) {
        const int b = mt * 16 + lq * 4 + r;
        outp[((size_t)s2 * 32 + b) * 44 + o] += acc0[r];
        outp[((size_t)t1 * 32 + b) * 44 + o] += acc1[r];
      }
    }
    return;
  }

  if (blockIdx.x >= 32) {
    // ================= GEMM role: xw chunk k (prepacked weights) =================
    if (k >= 16) return;
    const int gb = blockIdx.x - 32;
    const int ed = gb & 15, e = ed >> 1, d = ed & 1;
    const int slice = gb >> 4;
    const int nsl = L ? 10 : 14;
    unsigned short* xw = xwbufs + (size_t)(k & 1) * 16777216;

    s16x8 bf[4][KC];
    float bias[4];
#pragma unroll
    for (int j = 0; j < 4; ++j) {
      const int n = w * 64 + j * 16 + l15;
      bias[j] = biasb[ed * 512 + n];
      const unsigned short* wp = wihb + ((size_t)ed * 512 + n) * KS + lq * 8;
#pragma unroll
      for (int kc = 0; kc < KC; ++kc) bf[j][kc] = *(const s16x8*)(wp + kc * 32);
    }
    for (int ss = slice; ss < 64; ss += nsl) {
      const int s = k * 64 + ss;
      const int t = d ? 1023 - s : s;
#pragma unroll
      for (int mt = 0; mt < 2; ++mt) {
        const size_t arow = (size_t)(L ? (e * 1024 + t) : t) * 32 + mt * 16 + l15;
        const unsigned short* ap = Asrc + arow * KS + lq * 8;
        s16x8 af[KC];
#pragma unroll
        for (int kc = 0; kc < KC; ++kc) af[kc] = *(const s16x8*)(ap + kc * 32);
        f32x4 acc[4];
#pragma unroll
        for (int j = 0; j < 4; ++j) acc[j] = f32x4{bias[j], bias[j], bias[j], bias[j]};
#pragma unroll
        for (int kc = 0; kc < KC; ++kc) {
#pragma unroll
          for (int j = 0; j < 4; ++j) acc[j] = mfma16(af[kc], bf[j][kc], acc[j]);
        }
        unsigned short* op = xw + (((size_t)(ed * 2 + mt) * 64 + ss) * 512) * 16 + lq * 4;
#pragma unroll
        for (int j = 0; j < 4; ++j) {
          const int n = w * 64 + j * 16 + l15;
          ushort4 o4;
          o4.x = f2bf(acc[j][0]); o4.y = f2bf(acc[j][1]);
          o4.z = f2bf(acc[j][2]); o4.w = f2bf(acc[j][3]);
          *(ushort4*)(op + (size_t)n * 16) = o4;
        }
      }
    }
    return;
  }

  // ================= REC role: chunk c = k-1 (r7 structure + setprio) ============
  const int c = k - 1;
  if (c < 0 || c > 15) return;
  __builtin_amdgcn_s_setprio(2);  // T5: favor latency-critical rec waves on this CU
  const int rb = blockIdx.x, ed2 = rb >> 1, bh = rb & 1;
  const int e = ed2 >> 1, d = ed2 & 1;
  __shared__ __align__(16) char hbf[2][4096];
  const int cell = w * 16 + l15;

  s16x8 bfh[4][4];  // pre-scaled Whh
#pragma unroll
  for (int g = 0; g < 4; ++g) {
    const unsigned short* wp = whhb + ((size_t)ed2 * 512 + g * 128 + cell) * 128 + lq * 8;
#pragma unroll
    for (int kc = 0; kc < 4; ++kc) bfh[g][kc] = *(const s16x8*)(wp + kc * 32);
  }
  const int wb0 = ((cell >> 5) << 10) | (((cell >> 3) & 3) << 8) | ((cell & 7) << 1);
  float cst[4];
  unsigned short hb4[4];
  if (c == 0) {
#pragma unroll
    for (int r = 0; r < 4; ++r) { cst[r] = 0.f; hb4[r] = 0; }
    if (tid < 256) {
      s16x8 z = {0,0,0,0,0,0,0,0};
      *(s16x8*)(&hbf[0][tid * 16]) = z;
    }
  } else {
    const float* cp = cstate + ((size_t)rb * 512 + tid) * 4;
    const unsigned short* hp = hstate + ((size_t)rb * 512 + tid) * 4;
#pragma unroll
    for (int r = 0; r < 4; ++r) {
      cst[r] = cp[r];
      hb4[r] = hp[r];
      *(unsigned short*)(&hbf[0][wb0 | ((lq * 4 + r) << 4)]) = hp[r];
    }
  }
  __syncthreads();

  const unsigned short* xwb =
      xwbufs + (size_t)(c & 1) * 16777216 + ((size_t)(ed2 * 2 + bh) * 64) * 8192 + cell * 16 + lq * 4;
  const int brow = bh * 16 + lq * 4;

  ushort4 xq[4];
#pragma unroll
  for (int g = 0; g < 4; ++g) xq[g] = *(const ushort4*)(xwb + g * 2048);

  for (int tt = 0; tt < 64; ++tt) {
    const int p = tt & 1;
    // early: prefetch next xw (full step to complete before barrier drain)
    ushort4 nxq[4];
    {
      const int tn = tt < 63 ? tt + 1 : 63;
#pragma unroll
      for (int g = 0; g < 4; ++g) nxq[g] = *(const ushort4*)(xwb + (size_t)tn * 8192 + g * 2048);
    }
    // early: store previous step's h from register carry
    if (tt > 0) {
      const int ptt = tt - 1;
      size_t ob;
      if (L) {
        ob = (size_t)(c & 1) * 4194304 + (((size_t)e * 64 + ptt) * 32 + brow) * 256 + d * 128 + cell;
      } else {
        const int s = c * 64 + ptt;
        const int tg = d ? 1023 - s : s;
        ob = (((size_t)e * 1024 + tg) * 32 + brow) * 256 + d * 128 + cell;
      }
#pragma unroll
      for (int r = 0; r < 4; ++r) hout[ob + (size_t)r * 256] = hb4[r];
    }

    s16x8 hf[4];
#pragma unroll
    for (int kc = 0; kc < 4; ++kc) hf[kc] = *(const s16x8*)(&hbf[p][kc * 1024 + l * 16]);
    f32x4 a[4];
#pragma unroll
    for (int g = 0; g < 4; ++g) {
      a[g][0] = bf2f(xq[g].x); a[g][1] = bf2f(xq[g].y);
      a[g][2] = bf2f(xq[g].z); a[g][3] = bf2f(xq[g].w);
    }
#pragma unroll
    for (int kc = 0; kc < 4; ++kc) {
#pragma unroll
      for (int g = 0; g < 4; ++g) a[g] = mfma16(hf[kc], bfh[g][kc], a[g]);
    }

    // gates (pre-scaled inputs; overflow-safe clamps)
#pragma unroll
    for (int r = 0; r < 4; ++r) {
      const float ai = ex2(a[0][r]);
      const float af = ex2(a[1][r]);
      const float bg = ex2(fminf(a[2][r], 80.f));
      const float ao = ex2(a[3][r]);
      const float sf = rcp_(1.f + af);
      const float r1 = rcp_((1.f + ai) * (1.f + bg));
      const float bgm = __builtin_fmaf(bg, K2L, -K2L);
      const float cc = __builtin_fmaf(sf, cst[r], bgm * r1);
      cst[r] = cc;
      const float qc = ex2(fminf(cc, 80.f));
      const float r2 = rcp_((1.f + ao) * (1.f + qc));
      hb4[r] = f2bf((qc - 1.f) * r2);
    }
    char* hw = &hbf[1 - p][0];
#pragma unroll
    for (int r = 0; r < 4; ++r)
      *(unsigned short*)(hw + (wb0 | ((lq * 4 + r) << 4))) = hb4[r];
    __syncthreads();
#pragma unroll
    for (int g = 0; g < 4; ++g) xq[g] = nxq[g];
  }

  // epilogue: store h(63) + carry state
  {
    size_t ob;
    if (L) {
      ob = (size_t)(c & 1) * 4194304 + (((size_t)e * 64 + 63) * 32 + brow) * 256 + d * 128 + cell;
    } else {
      const int s = c * 64 + 63;
      const int tg = d ? 1023 - s : s;
      ob = (((size_t)e * 1024 + tg) * 32 + brow) * 256 + d * 128 + cell;
    }
#pragma unroll
    for (int r = 0; r < 4; ++r) hout[ob + (size_t)r * 256] = hb4[r];
    unsigned short* hsp = hstate + ((size_t)rb * 512 + tid) * 4;
    float* csp = cstate + ((size_t)rb * 512 + tid) * 4;
#pragma unroll
    for (int r = 0; r < 4; ++r) { hsp[r] = hb4[r]; csp[r] = cst[r]; }
  }
  __builtin_amdgcn_s_setprio(0);
}

// ---------------------------------------------------------------- launch
extern "C" void kernel_launch(void* const* d_in, const int* in_sizes, int n_in,
                              void* d_out, int out_size, void* d_ws, size_t ws_size,
                              hipStream_t stream) {
  const float* x    = (const float*)d_in[0];
  const float* spk  = (const float*)d_in[1];
  const float* wgw  = (const float*)d_in[2];
  const float* wgb  = (const float*)d_in[3];
  const float* Wih0 = (const float*)d_in[4];
  const float* Whh0 = (const float*)d_in[5];
  const float* bih0 = (const float*)d_in[6];
  const float* bhh0 = (const float*)d_in[7];
  const float* Wih1 = (const float*)d_in[8];
  const float* Whh1 = (const float*)d_in[9];
  const float* bih1 = (const float*)d_in[10];
  const float* bhh1 = (const float*)d_in[11];
  const float* fc1w = (const float*)d_in[12];
  const float* fc1b = (const float*)d_in[13];
  const float* fcw  = (const float*)d_in[14];
  const float* fcb  = (const float*)d_in[15];
  float* out = (float*)d_out;

  if (ws_size < (size_t)WS_NEED) {
    wsdbg_kernel<<<1, 1, 0, stream>>>(out, (float)(ws_size >> 20));
    return;
  }
  char* ws = (char*)d_ws;
  unsigned short* h0     = (unsigned short*)(ws + OFF_H0);
  unsigned short* xwbufs = (unsigned short*)(ws + OFF_XW);
  unsigned short* xt     = (unsigned short*)(ws + OFF_XT);
  unsigned short* whhb   = (unsigned short*)(ws + OFF_WHH);
  unsigned short* h1c    = (unsigned short*)(ws + OFF_H1C);
  unsigned short* hstate = (unsigned short*)(ws + OFF_HST);
  float*          cstate = (float*)(ws + OFF_CST);
  float*          Mmat   = (float*)(ws + OFF_M);
  float*          Cv     = (float*)(ws + OFF_CV);
  float*          gatesw = (float*)(ws + OFF_G);
  unsigned short* wihb0  = (unsigned short*)(ws + OFF_WIH0);
  unsigned short* wihb1  = (unsigned short*)(ws + OFF_WIH1);
  float*          biasb  = (float*)(ws + OFF_BIA);

  prep_kernel<<<4096, 512, 0, stream>>>(Whh0, Whh1, Wih0, Wih1, bih0, bhh0, bih1, bhh1,
                                        whhb, wihb0, wihb1, biasb);
  prepx_kernel<<<4096, 512, 0, stream>>>(x, xt);
  mprep_kernel<<<48, 256, 0, stream>>>(fc1w, fc1b, fcw, fcb, Mmat, Cv);
  initout_kernel<<<2816, 512, 0, stream>>>(Cv, out);
  gating_kernel<<<1, 256, 0, stream>>>(spk, wgw, wgb, gatesw, out + 1441792);

  for (int k = 0; k <= 16; ++k)
    fused<0><<<256, 512, 0, stream>>>(k, xt, wihb0, biasb, whhb, xwbufs,
                                      hstate, cstate, h0, nullptr, nullptr, out);
  for (int k = 0; k <= 17; ++k)
    fused<1><<<256, 512, 0, stream>>>(k, h0, wihb1, biasb + 8192, whhb + 1048576, xwbufs,
                                      hstate, cstate, h1c, Mmat, gatesw, out);
}